// Round 2
// 749.737 us; speedup vs baseline: 1.0501x; 1.0501x over previous
//
#include <hip/hip_runtime.h>
#include <hip/hip_bf16.h>

#define NUM_EXPERTS 32
#define HIDDEN 2048
#define INTER 768
#define TOPK 4
#define T_TOKENS 1024
#define CAP 1024

#define MT 64       // token slots per block (z-split x3, stride-192 safety loop)
#define BK 64       // K step
#define LSTR 72     // LDS row stride in bf16 elements (16B-multiple)

typedef __bf16 bf16x8 __attribute__((ext_vector_type(8)));
typedef float floatx4 __attribute__((ext_vector_type(4)));

// XOR-swizzled LDS element offset: row-major stride LSTR, 8-elem (16B) k-blocks
// swizzled by row>>2 to break the n=4*lane staging-write bank pattern.
__device__ __forceinline__ int swz(int row, int kq) {
    return row * LSTR + (((kq ^ (row >> 2)) & 7) << 3);
}

// ---------------------------------------------------------------- routing ---
__global__ void route_kernel(const int* __restrict__ ri, int* __restrict__ counts,
                             int* __restrict__ tok_list) {
    int t = blockIdx.x * blockDim.x + threadIdx.x;
    if (t >= T_TOKENS) return;
    int idx[TOPK];
#pragma unroll
    for (int j = 0; j < TOPK; ++j) idx[j] = ri[t * TOPK + j];
#pragma unroll
    for (int j = 0; j < TOPK; ++j) {
        int e = idx[j];
        bool dup = false;
#pragma unroll
        for (int l = 0; l < TOPK; ++l)
            if (l < j && idx[l] == e) dup = true;
        if (!dup) {
            int s = atomicAdd(&counts[e], 1);
            tok_list[e * CAP + s] = t;
        }
    }
}

// ------------------------------------------------------- gemm1: x @ Wgu -----
// grid (3*INTER/64, E). z-split folded into x (fastest) so the 3 readers of the
// same weight slab are co-resident -> redundant reads hit L3.
// T14 async-STAGE: issue next K-tile's global loads into regs BEFORE the MFMA
// phase; vmcnt-wait + f32->bf16 convert + ds_write AFTER the post-MFMA barrier.
__global__ __launch_bounds__(256) void gemm1_kernel(
    const float* __restrict__ x, const float* __restrict__ rw,
    const float* __restrict__ Wgu, const int* __restrict__ counts,
    const int* __restrict__ tok_list, __bf16* __restrict__ act) {
    const int e = blockIdx.y;
    const int zi = blockIdx.x % 3;
    const int n0 = (blockIdx.x / 3) * 64;
    const int count = counts[e];
    const int tid = threadIdx.x;
    const int wave = tid >> 6;
    const int lane = tid & 63;
    const int fr = lane & 15;
    const int fq = lane >> 4;
    const int wr = wave >> 1;   // wave M-half
    const int wc = wave & 1;    // wave N-half

    __shared__ int s_off;
    __shared__ int s_tok[MT];
    __shared__ float s_w[MT];
    __shared__ __align__(16) __bf16 As[MT * LSTR];
    __shared__ __align__(16) __bf16 Bs[128 * LSTR];

    if (tid == 0) {
        int o = 0;
        for (int i = 0; i < e; ++i) o += counts[i];
        s_off = o;
    }

    const size_t wbase = (size_t)e * HIDDEN * (2 * INTER);

    // B staging geometry (constant across k0): thread owns 4 adjacent n, 8 k rows
    const int ng = (tid & 31) * 4;          // Bs row base (0..124)
    const int kg = tid >> 5;                // 8-k group (0..7)
    const int bwc = ng >> 6;
    const int bj = ng & 63;
    const int memcol = (bj < 32) ? (n0 + bwc * 32 + bj)
                                 : (INTER + n0 + bwc * 32 + (bj - 32));
    // A staging geometry
    const int ar = tid >> 2;                // row 0..63
    const int aq = tid & 3;                 // 16-k quarter

    for (int m0 = zi * MT; m0 < count; m0 += 3 * MT) {
        __syncthreads();
        if (tid < MT) {
            int slot = m0 + tid;
            int t = (slot < count) ? tok_list[e * CAP + slot] : tok_list[e * CAP];
            s_tok[tid] = t;
            s_w[tid] = (slot < count) ? rw[t * NUM_EXPERTS + e] : 0.f;
        }
        __syncthreads();

        const float* aRow = x + (size_t)s_tok[ar] * HIDDEN + aq * 16;
        const float* bCol = Wgu + wbase + (size_t)(kg * 8) * (2 * INTER) + memcol;

        float4 pa[4], pb[8];
        auto loadA = [&](int kbase) {
            const float4* s = (const float4*)(aRow + kbase);
#pragma unroll
            for (int i = 0; i < 4; ++i) pa[i] = s[i];
        };
        auto loadB = [&](int kbase) {
#pragma unroll
            for (int r8 = 0; r8 < 8; ++r8)
                pb[r8] = *(const float4*)(bCol + (size_t)(kbase + r8) * (2 * INTER));
        };
        auto writeA = [&]() {
            bf16x8 p0, p1;
            p0[0] = (__bf16)pa[0].x; p0[1] = (__bf16)pa[0].y; p0[2] = (__bf16)pa[0].z; p0[3] = (__bf16)pa[0].w;
            p0[4] = (__bf16)pa[1].x; p0[5] = (__bf16)pa[1].y; p0[6] = (__bf16)pa[1].z; p0[7] = (__bf16)pa[1].w;
            p1[0] = (__bf16)pa[2].x; p1[1] = (__bf16)pa[2].y; p1[2] = (__bf16)pa[2].z; p1[3] = (__bf16)pa[2].w;
            p1[4] = (__bf16)pa[3].x; p1[5] = (__bf16)pa[3].y; p1[6] = (__bf16)pa[3].z; p1[7] = (__bf16)pa[3].w;
            *(bf16x8*)&As[swz(ar, 2 * aq)] = p0;
            *(bf16x8*)&As[swz(ar, 2 * aq + 1)] = p1;
        };
        auto writeB = [&]() {
#pragma unroll
            for (int c = 0; c < 4; ++c) {
                bf16x8 p;
#pragma unroll
                for (int r8 = 0; r8 < 8; ++r8)
                    p[r8] = (__bf16)((const float*)&pb[r8])[c];
                *(bf16x8*)&Bs[swz(ng + c, kg)] = p;
            }
        };

        floatx4 acc[2][4];
#pragma unroll
        for (int ms = 0; ms < 2; ++ms)
#pragma unroll
            for (int nf = 0; nf < 4; ++nf)
                acc[ms][nf] = (floatx4){0.f, 0.f, 0.f, 0.f};

        // prologue: stage K-tile 0
        loadA(0); loadB(0);
        writeA(); writeB();
        __syncthreads();

        for (int k0 = 0; k0 < HIDDEN; k0 += BK) {
            const bool has_next = (k0 + BK < HIDDEN);
            if (has_next) { loadA(k0 + BK); loadB(k0 + BK); }  // issue-early

#pragma unroll
            for (int ks = 0; ks < 2; ++ks) {
                bf16x8 af[2], bf[4];
#pragma unroll
                for (int ms = 0; ms < 2; ++ms)
                    af[ms] = *(const bf16x8*)&As[swz(wr * 32 + ms * 16 + fr, ks * 4 + fq)];
#pragma unroll
                for (int nf = 0; nf < 4; ++nf)
                    bf[nf] = *(const bf16x8*)&Bs[swz(wc * 64 + nf * 16 + fr, ks * 4 + fq)];
#pragma unroll
                for (int ms = 0; ms < 2; ++ms)
#pragma unroll
                    for (int nf = 0; nf < 4; ++nf)
                        acc[ms][nf] = __builtin_amdgcn_mfma_f32_16x16x32_bf16(af[ms], bf[nf], acc[ms][nf], 0, 0, 0);
            }
            __syncthreads();                 // all waves done reading LDS
            if (has_next) { writeA(); writeB(); }  // write-late (vmcnt waits here)
            __syncthreads();
        }

        // epilogue: silu(gate)*up*rw -> act bf16 (frags nf<2 gate, nf>=2 up)
        const int off = s_off;
#pragma unroll
        for (int ms = 0; ms < 2; ++ms) {
            int rbase = wr * 32 + ms * 16 + fq * 4;
#pragma unroll
            for (int i = 0; i < 4; ++i) {
                int slot = m0 + rbase + i;
                if (slot < count) {
                    float w = s_w[rbase + i];
#pragma unroll
                    for (int nf = 0; nf < 2; ++nf) {
                        float gv = acc[ms][nf][i];
                        float uv = acc[ms][nf + 2][i];
                        float a = gv / (1.f + __expf(-gv)) * uv * w;
                        act[(size_t)(off + slot) * INTER + n0 + wc * 32 + nf * 16 + fr] = (__bf16)a;
                    }
                }
            }
        }
    }
}

// ------------------------------------------------- gemm2: act @ Wd -> out ---
// grid (3*HIDDEN/128, E). Same T14 structure; N=128 out cols.
__global__ __launch_bounds__(256) void gemm2_kernel(
    const __bf16* __restrict__ act, const float* __restrict__ Wd,
    const int* __restrict__ counts, const int* __restrict__ tok_list,
    float* __restrict__ out) {
    const int e = blockIdx.y;
    const int zi = blockIdx.x % 3;
    const int n0 = (blockIdx.x / 3) * 128;
    const int count = counts[e];
    const int tid = threadIdx.x;
    const int wave = tid >> 6;
    const int lane = tid & 63;
    const int fr = lane & 15;
    const int fq = lane >> 4;
    const int wr = wave >> 1;
    const int wc = wave & 1;

    __shared__ int s_off;
    __shared__ int s_tok[MT];
    __shared__ __align__(16) __bf16 As[MT * LSTR];
    __shared__ __align__(16) __bf16 Bs[128 * LSTR];

    if (tid == 0) {
        int o = 0;
        for (int i = 0; i < e; ++i) o += counts[i];
        s_off = o;
    }

    const size_t wbase = (size_t)e * INTER * HIDDEN;
    const int ng = (tid & 31) * 4;
    const int kg = tid >> 5;
    const int ar = tid >> 2;
    const int aq = tid & 3;

    for (int m0 = zi * MT; m0 < count; m0 += 3 * MT) {
        __syncthreads();
        if (tid < MT) {
            int slot = m0 + tid;
            s_tok[tid] = (slot < count) ? tok_list[e * CAP + slot] : 0;
        }
        __syncthreads();

        const __bf16* aRow = act + (size_t)(s_off + min(m0 + ar, count - 1)) * INTER + aq * 16;
        const float* bCol = Wd + wbase + (size_t)(kg * 8) * HIDDEN + n0 + ng;

        bf16x8 qa[2];
        float4 pb[8];
        auto loadA = [&](int kbase) {
            const bf16x8* s = (const bf16x8*)(aRow + kbase);
            qa[0] = s[0];
            qa[1] = s[1];
        };
        auto loadB = [&](int kbase) {
#pragma unroll
            for (int r8 = 0; r8 < 8; ++r8)
                pb[r8] = *(const float4*)(bCol + (size_t)(kbase + r8) * HIDDEN);
        };
        auto writeA = [&]() {
            *(bf16x8*)&As[swz(ar, 2 * aq)] = qa[0];
            *(bf16x8*)&As[swz(ar, 2 * aq + 1)] = qa[1];
        };
        auto writeB = [&]() {
#pragma unroll
            for (int c = 0; c < 4; ++c) {
                bf16x8 p;
#pragma unroll
                for (int r8 = 0; r8 < 8; ++r8)
                    p[r8] = (__bf16)((const float*)&pb[r8])[c];
                *(bf16x8*)&Bs[swz(ng + c, kg)] = p;
            }
        };

        floatx4 acc[2][4];
#pragma unroll
        for (int ms = 0; ms < 2; ++ms)
#pragma unroll
            for (int nf = 0; nf < 4; ++nf)
                acc[ms][nf] = (floatx4){0.f, 0.f, 0.f, 0.f};

        // prologue: stage K-tile 0
        loadA(0); loadB(0);
        writeA(); writeB();
        __syncthreads();

        for (int k0 = 0; k0 < INTER; k0 += BK) {
            const bool has_next = (k0 + BK < INTER);
            if (has_next) { loadA(k0 + BK); loadB(k0 + BK); }  // issue-early

#pragma unroll
            for (int ks = 0; ks < 2; ++ks) {
                bf16x8 af[2], bf[4];
#pragma unroll
                for (int ms = 0; ms < 2; ++ms)
                    af[ms] = *(const bf16x8*)&As[swz(wr * 32 + ms * 16 + fr, ks * 4 + fq)];
#pragma unroll
                for (int nf = 0; nf < 4; ++nf)
                    bf[nf] = *(const bf16x8*)&Bs[swz(wc * 64 + nf * 16 + fr, ks * 4 + fq)];
#pragma unroll
                for (int ms = 0; ms < 2; ++ms)
#pragma unroll
                    for (int nf = 0; nf < 4; ++nf)
                        acc[ms][nf] = __builtin_amdgcn_mfma_f32_16x16x32_bf16(af[ms], bf[nf], acc[ms][nf], 0, 0, 0);
            }
            __syncthreads();
            if (has_next) { writeA(); writeB(); }  // write-late
            __syncthreads();
        }

        // epilogue: scatter-accumulate f32 atomics
#pragma unroll
        for (int ms = 0; ms < 2; ++ms) {
            int rbase = wr * 32 + ms * 16 + fq * 4;
#pragma unroll
            for (int i = 0; i < 4; ++i) {
                int slot = m0 + rbase + i;
                if (slot < count) {
                    int t = s_tok[rbase + i];
#pragma unroll
                    for (int nf = 0; nf < 4; ++nf)
                        atomicAdd(&out[(size_t)t * HIDDEN + n0 + wc * 64 + nf * 16 + fr], acc[ms][nf][i]);
                }
            }
        }
    }
}

// ---------------------------------------------------------------- launch ----
extern "C" void kernel_launch(void* const* d_in, const int* in_sizes, int n_in,
                              void* d_out, int out_size, void* d_ws, size_t ws_size,
                              hipStream_t stream) {
    const float* x   = (const float*)d_in[0];
    const float* rw  = (const float*)d_in[1];
    const float* Wgu = (const float*)d_in[2];
    const float* Wd  = (const float*)d_in[3];
    const int*   ri  = (const int*)d_in[4];
    float* out = (float*)d_out;

    int* counts   = (int*)d_ws;
    int* tok_list = (int*)((char*)d_ws + 512);
    __bf16* act   = (__bf16*)((char*)d_ws + 512 + NUM_EXPERTS * CAP * 4);

    hipMemsetAsync(d_ws, 0, 512, stream);
    hipMemsetAsync(d_out, 0, (size_t)T_TOKENS * HIDDEN * sizeof(float), stream);

    route_kernel<<<dim3(T_TOKENS / 256), 256, 0, stream>>>(ri, counts, tok_list);
    gemm1_kernel<<<dim3(3 * INTER / 64, NUM_EXPERTS), 256, 0, stream>>>(x, rw, Wgu, counts, tok_list, act);
    gemm2_kernel<<<dim3(3 * HIDDEN / 128, NUM_EXPERTS), 256, 0, stream>>>(act, Wd, counts, tok_list, out);
}